// Round 1
// 382.805 us; speedup vs baseline: 1.0857x; 1.0857x over previous
//
#include <hip/hip_runtime.h>

// ---------------- problem constants ----------------
constexpr int cN     = 20000;
constexpr int cT     = 8;
constexpr int cFIN   = 64;
constexpr int cHEADS = 4;
constexpr int cF     = 32;
constexpr int cHID   = 128;        // cHEADS * cF
constexpr int cE     = 320000;
constexpr int cET    = cE + cN;    // edges + self loops
constexpr int cR     = cN * cT;    // 160000 batched rows, rho = t*N + n (t-major)
constexpr float cLEAKY = 0.2f;
constexpr float cL2E = 1.44269504088896340736f;   // log2(e)

typedef __attribute__((ext_vector_type(8))) short bf16x8;   // MFMA A/B frag
typedef __attribute__((ext_vector_type(4))) float f32x4;    // MFMA C/D frag

static __device__ __forceinline__ unsigned short f2bfu(float f) {
    unsigned int u;
    __builtin_memcpy(&u, &f, 4);
    u += 0x7FFFu + ((u >> 16) & 1u);
    return (unsigned short)(u >> 16);
}
static __device__ __forceinline__ void unpack2(unsigned int v, float& lo, float& hi) {
    unsigned int ul = v << 16, uh = v & 0xFFFF0000u;
    __builtin_memcpy(&lo, &ul, 4);
    __builtin_memcpy(&hi, &uh, 4);
}
static __device__ __forceinline__ unsigned int pack2(float lo, float hi) {
    unsigned int ul, uh;
    __builtin_memcpy(&ul, &lo, 4);
    __builtin_memcpy(&uh, &hi, 4);
    ul += 0x7FFFu + ((ul >> 16) & 1u);
    uh += 0x7FFFu + ((uh >> 16) & 1u);
    return (ul >> 16) | (uh & 0xFFFF0000u);
}

// ---------------- weight conversion ----------------
__global__ void cvt_w_kernel(const float* W1, const float* W2, const float* lw1,
                             unsigned short* W1b, unsigned short* W2b, unsigned short* lw1b) {
    int i = blockIdx.x * 256 + threadIdx.x;
    if (i < cHID * cFIN)                      W1b[i] = f2bfu(W1[i]);
    else if (i < cHID * cFIN + cHID * cHID)   W2b[i - cHID * cFIN] = f2bfu(W2[i - cHID * cFIN]);
    else if (i < cHID * cFIN + cHID * cHID + cF * cHID)
        lw1b[i - cHID * cFIN - cHID * cHID] = f2bfu(lw1[i - cHID * cFIN - cHID * cHID]);
}

// ---------------- CSR build ----------------
__global__ void deg_init_kernel(int* deg) {
    int n = blockIdx.x * blockDim.x + threadIdx.x;
    if (n < cN) deg[n] = 1;   // self loop
}
__global__ void deg_count_kernel(const int* ei, int* deg) {
    int e = blockIdx.x * blockDim.x + threadIdx.x;
    if (e < cE) atomicAdd(&deg[ei[cE + e]], 1);
}
// LDS-staged scan: coalesced global loads, then per-thread chunk prefix.
__global__ void scan_kernel(const int* deg, int* offs, int* cur) {
    __shared__ int sdeg[79 * 256];     // 20224 >= cN
    __shared__ int lds[256];
    int tid = threadIdx.x;
    #pragma unroll 4
    for (int k = 0; k < 79; k++) {
        int idx = k * 256 + tid;
        sdeg[idx] = (idx < cN) ? deg[idx] : 0;
    }
    __syncthreads();
    const int CH = 79;
    int base = tid * CH;
    int tot = 0;
    #pragma unroll 8
    for (int j = 0; j < CH; j++) tot += sdeg[base + j];
    lds[tid] = tot;
    __syncthreads();
    for (int off = 1; off < 256; off <<= 1) {
        int v = (tid >= off) ? lds[tid - off] : 0;
        __syncthreads();
        lds[tid] += v;
        __syncthreads();
    }
    int run = lds[tid] - tot;
    for (int j = 0; j < CH; j++) {
        int idx = base + j;
        if (idx < cN) { offs[idx] = run; cur[idx] = run; run += sdeg[idx]; }
    }
    if (tid == 255) offs[cN] = lds[255];
}
__global__ void scatter_kernel(const int* ei, int* cur, int* csr) {
    int e = blockIdx.x * blockDim.x + threadIdx.x;
    if (e >= cET) return;
    int s, d;
    if (e < cE) { s = ei[e]; d = ei[cE + e]; }
    else        { s = e - cE; d = s; }
    int pos = atomicAdd(&cur[d], 1);
    csr[pos] = s;
}

// ---------------- GEMM1 (fused fp32->bf16 cvt of x) + scores ----------------
// scores written pre-scaled by log2(e) so agg uses bare v_exp_f32 (exp2).
__global__ __launch_bounds__(256) void gemm1_fused_kernel(
        const float* __restrict__ x, const unsigned short* __restrict__ W,
        const float* __restrict__ a_src, const float* __restrict__ a_dst,
        unsigned short* __restrict__ hb, float* __restrict__ es, float* __restrict__ ed) {
    __shared__ float hl[64][132];
    int tid  = threadIdx.x;
    int wave = tid >> 6;
    int lane = tid & 63;
    int q    = lane >> 4;
    int mi   = lane & 15;
    int m0   = blockIdx.x * 64 + wave * 16;

    int rho = m0 + mi;
    int t = rho / cN;
    int n = rho - t * cN;
    const float* xr = x + (size_t)n * (cT * cFIN) + t * cFIN;

    bf16x8 afrag[2];
    #pragma unroll
    for (int s = 0; s < 2; s++) {
        float4 v0 = *(const float4*)(xr + s * 32 + q * 8);
        float4 v1 = *(const float4*)(xr + s * 32 + q * 8 + 4);
        bf16x8 f;
        f[0] = (short)f2bfu(v0.x); f[1] = (short)f2bfu(v0.y);
        f[2] = (short)f2bfu(v0.z); f[3] = (short)f2bfu(v0.w);
        f[4] = (short)f2bfu(v1.x); f[5] = (short)f2bfu(v1.y);
        f[6] = (short)f2bfu(v1.z); f[7] = (short)f2bfu(v1.w);
        afrag[s] = f;
    }

    f32x4 acc[8];
    #pragma unroll
    for (int ct = 0; ct < 8; ct++) acc[ct] = (f32x4){0.f, 0.f, 0.f, 0.f};
    #pragma unroll
    for (int ct = 0; ct < 8; ct++) {
        int c = ct * 16 + mi;
        #pragma unroll
        for (int s = 0; s < 2; s++) {
            bf16x8 bfrag = *(const bf16x8*)(W + (size_t)c * cFIN + s * 32 + q * 8);
            acc[ct] = __builtin_amdgcn_mfma_f32_16x16x32_bf16(afrag[s], bfrag, acc[ct], 0, 0, 0);
        }
    }

    #pragma unroll
    for (int ct = 0; ct < 8; ct++)
        #pragma unroll
        for (int r = 0; r < 4; r++)
            hl[wave * 16 + q * 4 + r][ct * 16 + mi] = acc[ct][r];
    __syncthreads();

    {
        int r2 = tid & 63;
        int hd = tid >> 6;
        int rg = blockIdx.x * 64 + r2;
        const float* hr = &hl[r2][hd * cF];
        const float* sa = a_src + hd * cF;
        const float* da = a_dst + hd * cF;
        float s1 = 0.f, s2 = 0.f;
        #pragma unroll 8
        for (int f = 0; f < cF; f++) {
            float hv = hr[f];
            s1 += hv * sa[f];
            s2 += hv * da[f];
        }
        es[rg * cHEADS + hd] = s1 * cL2E;
        ed[rg * cHEADS + hd] = s2 * cL2E;
    }

    size_t base = (size_t)blockIdx.x * 64 * cHID;
    #pragma unroll
    for (int it = 0; it < 8; it++) {
        int g   = tid + it * 256;
        int row = g >> 5;
        int c4  = (g & 31) * 4;
        float4 v = *(const float4*)&hl[row][c4];
        unsigned int p0 = pack2(v.x, v.y), p1 = pack2(v.z, v.w);
        *(uint2*)(hb + base + (size_t)row * cHID + c4) = make_uint2(p0, p1);
    }
}

// ---------------- agg core: one (row, 8-feature slice) per thread ----------------
// scores es/ed are pre-scaled by log2(e); w = exp2(leaky(es+ed)).
static __device__ __forceinline__ void agg_core(
        const unsigned short* __restrict__ hb, const float* __restrict__ es,
        const float* __restrict__ ed, const int* __restrict__ offs,
        const int* __restrict__ csr, const float* __restrict__ bias,
        int t, int n, int j, float* r) {
    int head = j >> 2;
    int rho  = t * cN + n;
    int s0 = offs[n], s1 = offs[n + 1];
    float edn = ed[(size_t)rho * cHEADS + head];
    const char* hpc = (const char*)(hb + (size_t)t * cN * cHID);     // plane base
    const char* epc = (const char*)(es + (size_t)t * cN * cHEADS);
    const char* cc  = (const char*)csr;
    unsigned jo = (unsigned)j * 16u;
    unsigned ho = (unsigned)head * 4u;

    float acc[8] = {};
    float den = 0.f;
    int i = s0;
    for (; i + 3 < s1; i += 4) {
        unsigned io = (unsigned)i * 4u;
        int sa = *(const int*)(cc + io);
        int sb = *(const int*)(cc + io + 4u);
        int sc = *(const int*)(cc + io + 8u);
        int sd = *(const int*)(cc + io + 12u);
        uint4 ra = *(const uint4*)(hpc + (((unsigned)sa) << 8) + jo);
        uint4 rb = *(const uint4*)(hpc + (((unsigned)sb) << 8) + jo);
        uint4 rc = *(const uint4*)(hpc + (((unsigned)sc) << 8) + jo);
        uint4 rd = *(const uint4*)(hpc + (((unsigned)sd) << 8) + jo);
        float ea = *(const float*)(epc + (((unsigned)sa) << 4) + ho) + edn;
        float eb = *(const float*)(epc + (((unsigned)sb) << 4) + ho) + edn;
        float ec = *(const float*)(epc + (((unsigned)sc) << 4) + ho) + edn;
        float ee = *(const float*)(epc + (((unsigned)sd) << 4) + ho) + edn;
        ea = (ea >= 0.f) ? ea : cLEAKY * ea;
        eb = (eb >= 0.f) ? eb : cLEAKY * eb;
        ec = (ec >= 0.f) ? ec : cLEAKY * ec;
        ee = (ee >= 0.f) ? ee : cLEAKY * ee;
        float wa = __builtin_amdgcn_exp2f(ea), wb = __builtin_amdgcn_exp2f(eb);
        float wc = __builtin_amdgcn_exp2f(ec), wd = __builtin_amdgcn_exp2f(ee);
        den += wa; den += wb; den += wc; den += wd;
        float lo, hi;
        unpack2(ra.x, lo, hi); acc[0] += wa * lo; acc[1] += wa * hi;
        unpack2(ra.y, lo, hi); acc[2] += wa * lo; acc[3] += wa * hi;
        unpack2(ra.z, lo, hi); acc[4] += wa * lo; acc[5] += wa * hi;
        unpack2(ra.w, lo, hi); acc[6] += wa * lo; acc[7] += wa * hi;
        unpack2(rb.x, lo, hi); acc[0] += wb * lo; acc[1] += wb * hi;
        unpack2(rb.y, lo, hi); acc[2] += wb * lo; acc[3] += wb * hi;
        unpack2(rb.z, lo, hi); acc[4] += wb * lo; acc[5] += wb * hi;
        unpack2(rb.w, lo, hi); acc[6] += wb * lo; acc[7] += wb * hi;
        unpack2(rc.x, lo, hi); acc[0] += wc * lo; acc[1] += wc * hi;
        unpack2(rc.y, lo, hi); acc[2] += wc * lo; acc[3] += wc * hi;
        unpack2(rc.z, lo, hi); acc[4] += wc * lo; acc[5] += wc * hi;
        unpack2(rc.w, lo, hi); acc[6] += wc * lo; acc[7] += wc * hi;
        unpack2(rd.x, lo, hi); acc[0] += wd * lo; acc[1] += wd * hi;
        unpack2(rd.y, lo, hi); acc[2] += wd * lo; acc[3] += wd * hi;
        unpack2(rd.z, lo, hi); acc[4] += wd * lo; acc[5] += wd * hi;
        unpack2(rd.w, lo, hi); acc[6] += wd * lo; acc[7] += wd * hi;
    }
    for (; i < s1; i++) {
        int sa = *(const int*)(cc + (unsigned)i * 4u);
        uint4 ra = *(const uint4*)(hpc + (((unsigned)sa) << 8) + jo);
        float ea = *(const float*)(epc + (((unsigned)sa) << 4) + ho) + edn;
        ea = (ea >= 0.f) ? ea : cLEAKY * ea;
        float wa = __builtin_amdgcn_exp2f(ea);
        den += wa;
        float lo, hi;
        unpack2(ra.x, lo, hi); acc[0] += wa * lo; acc[1] += wa * hi;
        unpack2(ra.y, lo, hi); acc[2] += wa * lo; acc[3] += wa * hi;
        unpack2(ra.z, lo, hi); acc[4] += wa * lo; acc[5] += wa * hi;
        unpack2(ra.w, lo, hi); acc[6] += wa * lo; acc[7] += wa * hi;
    }
    float inv = 1.f / (den + 1e-16f);
    float4 b0 = *(const float4*)(bias + 8 * j);
    float4 b1v = *(const float4*)(bias + 8 * j + 4);
    float v0 = acc[0] * inv + b0.x;  r[0] = (v0 > 0.f) ? v0 : expm1f(v0);
    float v1 = acc[1] * inv + b0.y;  r[1] = (v1 > 0.f) ? v1 : expm1f(v1);
    float v2 = acc[2] * inv + b0.z;  r[2] = (v2 > 0.f) ? v2 : expm1f(v2);
    float v3 = acc[3] * inv + b0.w;  r[3] = (v3 > 0.f) ? v3 : expm1f(v3);
    float v4 = acc[4] * inv + b1v.x; r[4] = (v4 > 0.f) ? v4 : expm1f(v4);
    float v5 = acc[5] * inv + b1v.y; r[5] = (v5 > 0.f) ? v5 : expm1f(v5);
    float v6 = acc[6] * inv + b1v.z; r[6] = (v6 > 0.f) ? v6 : expm1f(v6);
    float v7 = acc[7] * inv + b1v.w; r[7] = (v7 > 0.f) ? v7 : expm1f(v7);
}

// ---------------- fused agg(layer1) + GEMM2 + scores2 ----------------
// block = (t, 16 dst nodes). agg tile -> LDS (XOR-swizzled bf16) -> 8 MFMA/wave
// (wave w owns output cols [w*32, w*32+32)) -> hb2 + es2/ed2. Kills the 82 MB
// xb2 round-trip and the standalone gemm2 dispatch.
__global__ __launch_bounds__(256) void agg_gemm_kernel(
        const unsigned short* __restrict__ hb, const float* __restrict__ es,
        const float* __restrict__ ed, const int* __restrict__ offs,
        const int* __restrict__ csr, const float* __restrict__ bias,
        const unsigned short* __restrict__ W2, const float* __restrict__ a_src,
        const float* __restrict__ a_dst, unsigned short* __restrict__ hb2,
        float* __restrict__ es2, float* __restrict__ ed2) {
    __shared__ unsigned short tile[16 * 128];   // x2 tile, bf16, XOR-swizzled rows
    __shared__ float hl[16][132];
    int b    = blockIdx.x;
    int t    = b & 7;
    int g    = b >> 3;
    int tid  = threadIdx.x;
    int lrow = tid >> 4;
    int j    = tid & 15;
    int n0   = g * 16;

    float r[8];
    agg_core(hb, es, ed, offs, csr, bias, t, n0 + lrow, j, r);
    {
        uint4 o;
        o.x = pack2(r[0], r[1]); o.y = pack2(r[2], r[3]);
        o.z = pack2(r[4], r[5]); o.w = pack2(r[6], r[7]);
        unsigned tb = (unsigned)lrow * 256u + (((unsigned)j * 16u) ^ (((unsigned)(lrow & 7)) << 4));
        *(uint4*)((char*)tile + tb) = o;
    }
    __syncthreads();

    // ---- in-block GEMM: h2 = x2 @ W2^T  (K=128) ----
    int wave = tid >> 6;
    int lane = tid & 63;
    int q    = lane >> 4;
    int mi   = lane & 15;
    bf16x8 afrag[4];
    #pragma unroll
    for (int s = 0; s < 4; s++) {
        unsigned addr = (unsigned)mi * 256u +
                        (((unsigned)(s * 64 + q * 16)) ^ (((unsigned)(mi & 7)) << 4));
        afrag[s] = *(const bf16x8*)((const char*)tile + addr);
    }
    f32x4 acc2[2];
    acc2[0] = (f32x4){0.f, 0.f, 0.f, 0.f};
    acc2[1] = (f32x4){0.f, 0.f, 0.f, 0.f};
    #pragma unroll
    for (int ct = 0; ct < 2; ct++) {
        int c = (wave * 2 + ct) * 16 + mi;
        #pragma unroll
        for (int s = 0; s < 4; s++) {
            bf16x8 bfrag = *(const bf16x8*)(W2 + (size_t)c * cHID + s * 32 + q * 8);
            acc2[ct] = __builtin_amdgcn_mfma_f32_16x16x32_bf16(afrag[s], bfrag, acc2[ct], 0, 0, 0);
        }
    }
    #pragma unroll
    for (int ct = 0; ct < 2; ct++)
        #pragma unroll
        for (int rr = 0; rr < 4; rr++)
            hl[q * 4 + rr][(wave * 2 + ct) * 16 + mi] = acc2[ct][rr];
    __syncthreads();

    if (tid < 64) {
        int r2 = tid & 15;
        int hd = tid >> 4;
        int rg = t * cN + n0 + r2;
        const float* hr = &hl[r2][hd * cF];
        const float* sa = a_src + hd * cF;
        const float* da = a_dst + hd * cF;
        float s1 = 0.f, s2 = 0.f;
        #pragma unroll 8
        for (int f = 0; f < cF; f++) {
            float hv = hr[f];
            s1 += hv * sa[f];
            s2 += hv * da[f];
        }
        es2[(size_t)rg * cHEADS + hd] = s1 * cL2E;
        ed2[(size_t)rg * cHEADS + hd] = s2 * cL2E;
    }
    {
        int row = tid >> 4;
        int c8  = (tid & 15) * 8;
        float4 v0 = *(const float4*)&hl[row][c8];
        float4 v1 = *(const float4*)&hl[row][c8 + 4];
        uint4 o;
        o.x = pack2(v0.x, v0.y); o.y = pack2(v0.z, v0.w);
        o.z = pack2(v1.x, v1.y); o.w = pack2(v1.z, v1.w);
        *(uint4*)(hb2 + (size_t)(t * cN + n0 + row) * cHID + c8) = o;
    }
}

// ---------------- fused agg(layer2) + MLP head -> out ----------------
__global__ __launch_bounds__(256) void TemporalGAT_20005957665499_kernel(
        const unsigned short* __restrict__ hb2, const float* __restrict__ es,
        const float* __restrict__ ed, const int* __restrict__ offs,
        const int* __restrict__ csr, const float* __restrict__ bias,
        const unsigned short* __restrict__ lw1b, const float* __restrict__ lb1,
        const float* __restrict__ lw2, const float* __restrict__ lb2,
        float* __restrict__ out) {
    __shared__ unsigned short tile[16 * 128];
    int b    = blockIdx.x;
    int t    = b & 7;
    int g    = b >> 3;
    int tid  = threadIdx.x;
    int lrow = tid >> 4;
    int j    = tid & 15;
    int n0   = g * 16;

    float r[8];
    agg_core(hb2, es, ed, offs, csr, bias, t, n0 + lrow, j, r);
    {
        uint4 o;
        o.x = pack2(r[0], r[1]); o.y = pack2(r[2], r[3]);
        o.z = pack2(r[4], r[5]); o.w = pack2(r[6], r[7]);
        unsigned tb = (unsigned)lrow * 256u + (((unsigned)j * 16u) ^ (((unsigned)(lrow & 7)) << 4));
        *(uint4*)((char*)tile + tb) = o;
    }
    __syncthreads();

    if (tid < 64) {      // wave 0: 16x128 @ 128x32 MLP, then dot with lw2
        int q  = tid >> 4;
        int mi = tid & 15;
        bf16x8 afrag[4];
        #pragma unroll
        for (int s = 0; s < 4; s++) {
            unsigned addr = (unsigned)mi * 256u +
                            (((unsigned)(s * 64 + q * 16)) ^ (((unsigned)(mi & 7)) << 4));
            afrag[s] = *(const bf16x8*)((const char*)tile + addr);
        }
        f32x4 acc2[2];
        acc2[0] = (f32x4){0.f, 0.f, 0.f, 0.f};
        acc2[1] = (f32x4){0.f, 0.f, 0.f, 0.f};
        #pragma unroll
        for (int ct = 0; ct < 2; ct++) {
            int c = ct * 16 + mi;
            #pragma unroll
            for (int s = 0; s < 4; s++) {
                bf16x8 bfrag = *(const bf16x8*)(lw1b + (size_t)c * cHID + s * 32 + q * 8);
                acc2[ct] = __builtin_amdgcn_mfma_f32_16x16x32_bf16(afrag[s], bfrag, acc2[ct], 0, 0, 0);
            }
        }
        float lb1a = lb1[mi], lb1b_ = lb1[16 + mi];
        float lw2a = lw2[mi], lw2b_ = lw2[16 + mi];
        float l2 = lb2[0];
        #pragma unroll
        for (int rr = 0; rr < 4; rr++) {
            float va = fmaxf(acc2[0][rr] + lb1a, 0.f);
            float vb = fmaxf(acc2[1][rr] + lb1b_, 0.f);
            float v = va * lw2a + vb * lw2b_;
            v += __shfl_xor(v, 1);
            v += __shfl_xor(v, 2);
            v += __shfl_xor(v, 4);
            v += __shfl_xor(v, 8);
            if (mi == 0) out[t * cN + n0 + q * 4 + rr] = v + l2;
        }
    }
}

// ---------------- launch ----------------
extern "C" void kernel_launch(void* const* d_in, const int* in_sizes, int n_in,
                              void* d_out, int out_size, void* d_ws, size_t ws_size,
                              hipStream_t stream) {
    const float* x   = (const float*)d_in[0];   // [N,T,64] fp32
    const int*   ei  = (const int*)d_in[1];
    const float* W1  = (const float*)d_in[2];
    const float* as1 = (const float*)d_in[3];
    const float* ad1 = (const float*)d_in[4];
    const float* b1  = (const float*)d_in[5];
    const float* W2  = (const float*)d_in[6];
    const float* as2 = (const float*)d_in[7];
    const float* ad2 = (const float*)d_in[8];
    const float* b2  = (const float*)d_in[9];
    const float* lw1 = (const float*)d_in[10];
    const float* lb1 = (const float*)d_in[11];
    const float* lw2 = (const float*)d_in[12];
    const float* lb2 = (const float*)d_in[13];
    float* out = (float*)d_out;                 // [T,N,1] fp32 == rho-major
    (void)in_sizes; (void)n_in; (void)out_size; (void)ws_size;

    // workspace carve, 256B-aligned
    char* ws = (char*)d_ws;
    size_t o = 0;
    auto carveN = [&](size_t bytes) { void* p = ws + o; o += (bytes + 255) & ~(size_t)255; return p; };
    unsigned short* hb   = (unsigned short*)carveN((size_t)cR * cHID * 2);    // 41 MB (layer-1 h)
    unsigned short* hb2  = (unsigned short*)carveN((size_t)cR * cHID * 2);    // 41 MB (layer-2 h)
    unsigned short* W1b  = (unsigned short*)carveN((size_t)cHID * cFIN * 2);
    unsigned short* W2b  = (unsigned short*)carveN((size_t)cHID * cHID * 2);
    unsigned short* lw1b = (unsigned short*)carveN((size_t)cF * cHID * 2);
    float* es1_buf = (float*)carveN((size_t)cR * cHEADS * 4);                 // 2.6 MB each
    float* ed1_buf = (float*)carveN((size_t)cR * cHEADS * 4);
    float* es2_buf = (float*)carveN((size_t)cR * cHEADS * 4);
    float* ed2_buf = (float*)carveN((size_t)cR * cHEADS * 4);
    int*   deg     = (int*)carveN((size_t)cN * 4);
    int*   offs    = (int*)carveN((size_t)(cN + 1) * 4);
    int*   cursor  = (int*)carveN((size_t)cN * 4);
    int*   csr     = (int*)carveN((size_t)cET * 4);

    // ---- weight conversion ----
    cvt_w_kernel<<<(cHID * cFIN + cHID * cHID + cF * cHID + 255) / 256, 256, 0, stream>>>(
        W1, W2, lw1, W1b, W2b, lw1b);

    // ---- CSR build ----
    deg_init_kernel<<<(cN + 255) / 256, 256, 0, stream>>>(deg);
    deg_count_kernel<<<(cE + 255) / 256, 256, 0, stream>>>(ei, deg);
    scan_kernel<<<1, 256, 0, stream>>>(deg, offs, cursor);
    scatter_kernel<<<(cET + 255) / 256, 256, 0, stream>>>(ei, cursor, csr);

    // ---- layer 1 GEMM (x read + cvt fused) ----
    gemm1_fused_kernel<<<cR / 64, 256, 0, stream>>>(x, W1b, as1, ad1, hb, es1_buf, ed1_buf);
    // ---- agg1 + GEMM2 + scores2 (fused) ----
    agg_gemm_kernel<<<(cN / 16) * cT, 256, 0, stream>>>(
        hb, es1_buf, ed1_buf, offs, csr, b1, W2b, as2, ad2, hb2, es2_buf, ed2_buf);
    // ---- agg2 + MLP head (fused) -> out ----
    TemporalGAT_20005957665499_kernel<<<(cN / 16) * cT, 256, 0, stream>>>(
        hb2, es2_buf, ed2_buf, offs, csr, b2, lw1b, lb1, lw2, lb2, out);
}